// Round 9
// baseline (254.089 us; speedup 1.0000x reference)
//
#include <hip/hip_runtime.h>

// FD_discretizer on fixed 1024x1024 grid, Ex=Ey=1026 extended grid.
// Round 9: packed-LDS variant of R8 + 4x-launch measurement probe.
//  - float2 SoA planes with all 0.5 face-averaging constants folded into the
//    stored values: phase-2 LDS ops drop ~64 -> ~33 per output, ~20 fewer
//    VALU mults/output. Explicit row-sharing across each thread's 2 outputs.
//  - __launch_bounds__(256,3): 3 waves/EU matches the 3-blocks/CU LDS limit
//    (42.24 KB) and allows ~170 VGPR without spill.
//  - kernel launched 4x back-to-back (idempotent, identical every call):
//    fd = (dur_total - ~145us fixed)/4 -- recovers per-dispatch timing that
//    the top-5 poison-fill cutoff has been hiding since R4.

#define NXC 1024               // NX == NY
#define EXC 1026               // Ex == Ey
#define NN  (NXC*NXC)

#define TB_ROWS 8
#define TB_COLS 64
#define H_ROWS  10             // TB_ROWS + 2
#define H_COLS  66             // TB_COLS + 2
#define NNODE   (H_ROWS*H_COLS)   // 660

extern "C" __global__ void __launch_bounds__(256, 3)
fd_kernel(const float* __restrict__ uvp,     // original_uv  n x 3
          const float* __restrict__ uvo,     // uv_old       n x 3
          const float* __restrict__ ndy,     // node_y       n x 3
          const float* __restrict__ ebm,     // ext metrics  n_ext x 5
          const float* __restrict__ dtg,     // dt           1
          const float* __restrict__ th,      // pde_theta    5
          const float* __restrict__ rl,      // relaxation   1
          float* __restrict__ out)
{
  const int bid = blockIdx.x;
  const int tid = threadIdx.x;

  const float dt   = dtg[0];
  const float uc   = th[0], cc = th[1], convc = th[2], pc = th[3], dc = th[4];
  const float relax= rl[0];
  const float rdt  = 1.f/dt;

  // packed SoA planes (42.24 KB total). Stored pre-scaled:
  //  sUV = 0.5*(u,v)        sQO = 0.5*(uo,vo)
  //  sCN = 0.5*(U,V)/1      sCO = 0.5*(Uo,Vo)   (U = (u*dxx+v*dxy)/J etc.)
  //  sAA = (a11,a22)        sPQ = 0.5*p/J*(dxx,dxy)   sPE = 0.5*p/J*(dex,dey)
  //  sP  = 0.5*p            sRJ = 2*rdt/J
  __shared__ float2 sUV[NNODE], sQO[NNODE], sCN[NNODE], sCO[NNODE],
                    sAA[NNODE], sPQ[NNODE], sPE[NNODE];
  __shared__ float  sP[NNODE], sRJ[NNODE];

  const int ctl = bid & 15, rt = bid >> 4;   // 16 col tiles x 128 row tiles
  const int X0e = ctl*TB_COLS;               // halo ext col base (0..960)
  const int J0e = rt*TB_ROWS;                // halo ext row base (0..1016)

  // ---- phase 1: stage 10x66 ext-halo nodes; BC ghosts in-line (R8-verified) --
  #pragma unroll
  for (int it=0; it<3; ++it){
    const int idx = tid + it*256;
    if (idx < NNODE){
      const int r  = idx / H_COLS;
      const int c  = idx - r*H_COLS;
      const int je = J0e + r;                // ext row in [0,1025]
      const int ie = X0e + c;                // ext col in [0,1025]
      const bool gB=(je==0), gT=(je==EXC-1), gL=(ie==0), gR=(ie==EXC-1);
      const bool onx=gL|gR, ony=gB|gT;

      float u,v,p,uo,vo;
      if (!(onx|ony)){
        const int g3 = 3*((je-1)*NXC + (ie-1));
        u=uvp[g3]; v=uvp[g3+1]; p=uvp[g3+2];
        uo=uvo[g3]; vo=uvo[g3+1];
        if (je==EXC/2 && ie==EXC/2) p = 0.f;           // PRESS_POINT (513,513)
      } else if (onx & ony){
        const int io = gL?0:NXC-1, jo = gB?0:NXC-1;    // corner: clipped interior
        const int g3 = 3*(jo*NXC+io);
        u=uvp[g3]; v=uvp[g3+1]; p=uvp[g3+2];
        uo=uvo[g3]; vo=uvo[g3+1];
      } else if (ony){
        // bottom/top WALL ghost: uv mirrored through dummy at g1; p from g2
        const int io = ie-1;
        const int j1 = gB?0:NXC-1, j2 = gB?1:NXC-2;
        const int m1 = 3*(j1*NXC+io), m2 = 3*(j2*NXC+io);
        const bool useF = (io==NXC-1);                 // OUTFLOW g1 -> dummy=field
        const float d1u = useF? uvp[m1]   : ndy[m1];
        const float d1v = useF? uvp[m1+1] : ndy[m1+1];
        u = 2.f*d1u - uvp[m2]; v = 2.f*d1v - uvp[m2+1]; p = uvp[m2+2];
        const float e1u = useF? uvo[m1]   : ndy[m1];
        const float e1v = useF? uvo[m1+1] : ndy[m1+1];
        uo = 2.f*e1u - uvo[m2]; vo = 2.f*e1v - uvo[m2+1];
      } else if (gL){
        // left INFLOW ghost: uv mirrored through node_y at col 0; p from col 1
        const int jo = je-1;
        const int m1 = 3*(jo*NXC), m2 = m1+3;
        const float d1u = ndy[m1], d1v = ndy[m1+1];
        u = 2.f*d1u - uvp[m2]; v = 2.f*d1v - uvp[m2+1]; p = uvp[m2+2];
        uo = 2.f*d1u - uvo[m2]; vo = 2.f*d1v - uvo[m2+1];
      } else {
        // right OUTFLOW ghost: uv copied from col 1022; p = -p[1022]
        const int m2 = 3*((je-1)*NXC + NXC-2);
        u = uvp[m2]; v = uvp[m2+1]; p = -uvp[m2+2];
        uo = uvo[m2]; vo = uvo[m2+1];
      }

      const int e5 = 5*(je*EXC + ie);
      const float dxx=ebm[e5], dxy=ebm[e5+1], dex=ebm[e5+2], dey=ebm[e5+3];
      const float rJ = 1.f/ebm[e5+4];

      const float uh=0.5f*u,  vh=0.5f*v, ph=0.5f*p;
      const float uoh=0.5f*uo, voh=0.5f*vo;
      sUV[idx] = make_float2(uh, vh);
      sQO[idx] = make_float2(uoh, voh);
      sCN[idx] = make_float2((uh*dxx + vh*dxy)*rJ, (uh*dex + vh*dey)*rJ);
      sCO[idx] = make_float2((uoh*dxx + voh*dxy)*rJ, (uoh*dex + voh*dey)*rJ);
      sAA[idx] = make_float2((dxx*dxx + dxy*dxy)*rJ, (dex*dex + dey*dey)*rJ);
      const float pq = ph*rJ;
      sPQ[idx] = make_float2(pq*dxx, pq*dxy);
      sPE[idx] = make_float2(pq*dex, pq*dey);
      sP [idx] = ph;
      sRJ[idx] = 2.f*rdt*rJ;
    }
  }
  __syncthreads();

  // ---- phase 2: 2 vertical outputs/thread with explicit row sharing ----
  const int tx = tid & 63, ty = tid >> 6;
  const int c  = 1 + tx;                     // halo col of centers

  // rows t=0..3 <-> halo rows 2ty..2ty+3; centers are t=1 (kk=0), t=2 (kk=1)
  float2 UVm[4], UVc[4], UVp[4], QOc[4], CNc[4], COc[4], AAc[4], PEc[4];
  float  Pm[4], Pc[4], Pp[4];
  #pragma unroll
  for (int t=0;t<4;++t){
    const int ib = (2*ty + t)*H_COLS + c;
    UVm[t]=sUV[ib-1]; UVc[t]=sUV[ib]; UVp[t]=sUV[ib+1];
    Pm[t]=sP[ib-1];   Pc[t]=sP[ib];   Pp[t]=sP[ib+1];
    QOc[t]=sQO[ib]; CNc[t]=sCN[ib]; COc[t]=sCO[ib]; AAc[t]=sAA[ib]; PEc[t]=sPE[ib];
  }
  float2 CNm[2], CNp[2], COm[2], COp[2], AAm[2], AAp[2], PQm[2], PQp[2], QOm[2], QOp[2];
  float  RJD[2];
  #pragma unroll
  for (int k=0;k<2;++k){
    const int ib = (2*ty + 1 + k)*H_COLS + c;
    CNm[k]=sCN[ib-1]; CNp[k]=sCN[ib+1];
    COm[k]=sCO[ib-1]; COp[k]=sCO[ib+1];
    AAm[k]=sAA[ib-1]; AAp[k]=sAA[ib+1];
    PQm[k]=sPQ[ib-1]; PQp[k]=sPQ[ib+1];
    QOm[k]=sQO[ib-1]; QOp[k]=sQO[ib+1];
    RJD[k]=sRJ[ib];
  }

  #pragma unroll
  for (int kk=0; kk<2; ++kk){
    const int tc = 1 + kk;                   // center row index in t-arrays

    // faces (0.5 factors pre-folded into sCN/sCO)
    const float Ufl = CNm[kk].x + CNc[tc].x, Ufr = CNc[tc].x + CNp[kk].x;
    const float Vfd = CNc[tc-1].y + CNc[tc].y, Vfu = CNc[tc].y + CNc[tc+1].y;
    const float Uflo= COm[kk].x + COc[tc].x, Ufro= COc[tc].x + COp[kk].x;
    const float Vfdo= COc[tc-1].y + COc[tc].y, Vfuo= COc[tc].y + COc[tc+1].y;

    const float loss = (Ufr - Ufl + Vfu - Vfd) * cc;

    const float u_c=UVc[tc].x, v_c=UVc[tc].y;
    const float uW =UVm[tc].x, vW =UVm[tc].y;
    const float uE =UVp[tc].x, vE =UVp[tc].y;
    const float uS =UVc[tc-1].x, vS =UVc[tc-1].y;
    const float uN =UVc[tc+1].x, vN =UVc[tc+1].y;

    const float cnu = (u_c+uE)*Ufr - (uW+u_c)*Ufl + (u_c+uN)*Vfu - (uS+u_c)*Vfd;
    const float cnv = (v_c+vE)*Ufr - (vW+v_c)*Ufl + (v_c+vN)*Vfu - (vS+v_c)*Vfd;

    const float uoc=QOc[tc].x, voc=QOc[tc].y;
    const float uoW=QOm[kk].x, voW=QOm[kk].y;
    const float uoE=QOp[kk].x, voE=QOp[kk].y;
    const float uoS=QOc[tc-1].x, voS=QOc[tc-1].y;
    const float uoN=QOc[tc+1].x, voN=QOc[tc+1].y;

    const float cou = (uoc+uoE)*Ufro - (uoW+uoc)*Uflo + (uoc+uoN)*Vfuo - (uoS+uoc)*Vfdo;
    const float cov = (voc+voE)*Ufro - (voW+voc)*Uflo + (voc+voN)*Vfuo - (voS+voc)*Vfdo;

    const float convu = relax*cou + (1.f-relax)*cnu;
    const float convv = relax*cov + (1.f-relax)*cnv;

    // diffusion (0.5 folded: halved uv against unscaled a11/a22 sums)
    const float axWC = AAm[kk].x + AAc[tc].x, axCE = AAc[tc].x + AAp[kk].x;
    const float aySC = AAc[tc-1].y + AAc[tc].y, ayCN = AAc[tc].y + AAc[tc+1].y;
    const float du = axCE*(uE-u_c) - axWC*(u_c-uW) + ayCN*(uN-u_c) - aySC*(u_c-uS);
    const float dv = axCE*(vE-v_c) - axWC*(v_c-vW) + ayCN*(vN-v_c) - aySC*(v_c-vS);

    const float gPx = (PQp[kk].x - PQm[kk].x) + (PEc[tc+1].x - PEc[tc-1].x);
    const float gPy = (PEc[tc+1].y - PEc[tc-1].y) + (PQp[kk].y - PQm[kk].y);

    const float unst_u = (u_c - uoc)*RJD[kk];
    const float unst_v = (v_c - voc)*RJD[kk];

    const float momu = uc*unst_u + convc*convu + pc*gPx - dc*du;
    const float momv = uc*unst_v + convc*convv + pc*gPy - dc*dv;

    // vis: halved values -> weight 0.125 instead of 0.0625
    const float visu=(UVm[tc-1].x+UVp[tc-1].x+UVm[tc+1].x+UVp[tc+1].x
                + 2.f*(UVc[tc-1].x+UVm[tc].x+UVp[tc].x+UVc[tc+1].x) + 4.f*u_c)*0.125f;
    const float visv=(UVm[tc-1].y+UVp[tc-1].y+UVm[tc+1].y+UVp[tc+1].y
                + 2.f*(UVc[tc-1].y+UVm[tc].y+UVp[tc].y+UVc[tc+1].y) + 4.f*v_c)*0.125f;
    const float visp=(Pm[tc-1]+Pp[tc-1]+Pm[tc+1]+Pp[tc+1]
                + 2.f*(Pc[tc-1]+Pm[tc]+Pp[tc]+Pc[tc+1]) + 4.f*Pc[tc])*0.125f;

    const int j = rt*TB_ROWS + 2*ty + kk;    // output row in [0,1023]
    const int o = j*NXC + X0e + tx;          // output col = X0e + tx
    out[o]        = loss;
    out[NN + o]   = momu;
    out[2*NN + o] = momv;
    const int vb = 3*NN + 3*o;
    out[vb]   = visu;
    out[vb+1] = visv;
    out[vb+2] = visp;
  }
}

extern "C" void kernel_launch(void* const* d_in, const int* in_sizes, int n_in,
                              void* d_out, int out_size, void* d_ws, size_t ws_size,
                              hipStream_t stream) {
  const float* uvp = (const float*)d_in[0];   // original_uv
  const float* uvo = (const float*)d_in[1];   // uv_old
  const float* ndy = (const float*)d_in[2];   // node_y
  const float* ebm = (const float*)d_in[4];   // extended_block_metrics
  const float* dtg = (const float*)d_in[5];   // dt_graph
  const float* th  = (const float*)d_in[6];   // pde_theta
  const float* rl  = (const float*)d_in[7];   // relaxtion
  float* out = (float*)d_out;

  // MEASUREMENT PROBE: 4 identical idempotent launches (same work every call,
  // graph-capture safe). fd_per_dispatch = (bench_total - ~145us fixed)/4.
  // Next round reverts to a single launch using this round's fd measurement.
  for (int rep=0; rep<4; ++rep){
    fd_kernel<<<dim3(2048), dim3(256), 0, stream>>>(uvp, uvo, ndy, ebm, dtg, th, rl, out);
  }
}

// Round 10
// 234.709 us; speedup vs baseline: 1.0826x; 1.0826x over previous
//
#include <hip/hip_runtime.h>

// FD_discretizer on fixed 1024x1024 grid, Ex=Ey=1026 extended grid.
// Round 10: counters probe + spill fix.
//  - Packed float2 SoA LDS planes with 0.5-face constants folded (R9 math,
//    verified absmax 0.125).
//  - Phase 2 reads DIRECTLY from LDS (no register pre-load arrays) and no
//    forced min-occupancy: R9's (256,3) + ~118-float arrays likely spilled
//    to scratch -- the invisible 2-3x in the cost model.
//  - The kernel body repeats 4x inside ONE dispatch (idempotent, barriers
//    between reps): surfaces fd above the 40us poison-fill cutoff so rocprof
//    finally reports its counters. fd_single ~ dur/4.

#define NXC 1024               // NX == NY
#define EXC 1026               // Ex == Ey
#define NN  (NXC*NXC)

#define TB_ROWS 8
#define TB_COLS 64
#define H_ROWS  10             // TB_ROWS + 2
#define H_COLS  66             // TB_COLS + 2
#define NNODE   (H_ROWS*H_COLS)   // 660

extern "C" __global__ void __launch_bounds__(256)
fd_kernel(const float* __restrict__ uvp,     // original_uv  n x 3
          const float* __restrict__ uvo,     // uv_old       n x 3
          const float* __restrict__ ndy,     // node_y       n x 3
          const float* __restrict__ ebm,     // ext metrics  n_ext x 5
          const float* __restrict__ dtg,     // dt           1
          const float* __restrict__ th,      // pde_theta    5
          const float* __restrict__ rl,      // relaxation   1
          float* __restrict__ out)
{
  const int bid = blockIdx.x;
  const int tid = threadIdx.x;

  const float dt   = dtg[0];
  const float uc   = th[0], cc = th[1], convc = th[2], pc = th[3], dc = th[4];
  const float relax= rl[0];
  const float rdt  = 1.f/dt;

  // packed SoA planes (42.24 KB). Stored pre-scaled:
  //  sUV = 0.5*(u,v)   sQO = 0.5*(uo,vo)
  //  sCN = 0.5*(U,V)   sCO = 0.5*(Uo,Vo)     (U=(u*dxx+v*dxy)/J, V=(u*dex+v*dey)/J)
  //  sAA = (a11,a22)   sPQ = 0.5*p/J*(dxx,dxy)   sPE = 0.5*p/J*(dex,dey)
  //  sP  = 0.5*p       sRJ = 2*rdt/J
  __shared__ float2 sUV[NNODE], sQO[NNODE], sCN[NNODE], sCO[NNODE],
                    sAA[NNODE], sPQ[NNODE], sPE[NNODE];
  __shared__ float  sP[NNODE], sRJ[NNODE];

  const int ctl = bid & 15, rt = bid >> 4;   // 16 col tiles x 128 row tiles
  const int X0e = ctl*TB_COLS;               // halo ext col base (0..960)
  const int J0e = rt*TB_ROWS;                // halo ext row base (0..1016)
  const int tx = tid & 63, ty = tid >> 6;
  const int c  = 1 + tx;                     // halo col of this thread's centers

  // ---- MEASUREMENT PROBE: 4 identical reps inside one dispatch ----
  for (int rep=0; rep<4; ++rep){
    __syncthreads();                         // previous rep's readers done

    // -- phase 1: stage 10x66 ext-halo nodes; BC ghosts in-line (R8-verified)
    #pragma unroll
    for (int it=0; it<3; ++it){
      const int idx = tid + it*256;
      if (idx < NNODE){
        const int r  = idx / H_COLS;
        const int cc2= idx - r*H_COLS;
        const int je = J0e + r;              // ext row in [0,1025]
        const int ie = X0e + cc2;            // ext col in [0,1025]
        const bool gB=(je==0), gT=(je==EXC-1), gL=(ie==0), gR=(ie==EXC-1);
        const bool onx=gL|gR, ony=gB|gT;

        float u,v,p,uo,vo;
        if (!(onx|ony)){
          const int g3 = 3*((je-1)*NXC + (ie-1));
          u=uvp[g3]; v=uvp[g3+1]; p=uvp[g3+2];
          uo=uvo[g3]; vo=uvo[g3+1];
          if (je==EXC/2 && ie==EXC/2) p = 0.f;         // PRESS_POINT (513,513)
        } else if (onx & ony){
          const int io = gL?0:NXC-1, jo = gB?0:NXC-1;  // corner: clipped interior
          const int g3 = 3*(jo*NXC+io);
          u=uvp[g3]; v=uvp[g3+1]; p=uvp[g3+2];
          uo=uvo[g3]; vo=uvo[g3+1];
        } else if (ony){
          // bottom/top WALL ghost: uv mirrored through dummy at g1; p from g2
          const int io = ie-1;
          const int j1 = gB?0:NXC-1, j2 = gB?1:NXC-2;
          const int m1 = 3*(j1*NXC+io), m2 = 3*(j2*NXC+io);
          const bool useF = (io==NXC-1);               // OUTFLOW g1 -> dummy=field
          const float d1u = useF? uvp[m1]   : ndy[m1];
          const float d1v = useF? uvp[m1+1] : ndy[m1+1];
          u = 2.f*d1u - uvp[m2]; v = 2.f*d1v - uvp[m2+1]; p = uvp[m2+2];
          const float e1u = useF? uvo[m1]   : ndy[m1];
          const float e1v = useF? uvo[m1+1] : ndy[m1+1];
          uo = 2.f*e1u - uvo[m2]; vo = 2.f*e1v - uvo[m2+1];
        } else if (gL){
          // left INFLOW ghost: uv mirrored through node_y at col 0; p from col 1
          const int jo = je-1;
          const int m1 = 3*(jo*NXC), m2 = m1+3;
          const float d1u = ndy[m1], d1v = ndy[m1+1];
          u = 2.f*d1u - uvp[m2]; v = 2.f*d1v - uvp[m2+1]; p = uvp[m2+2];
          uo = 2.f*d1u - uvo[m2]; vo = 2.f*d1v - uvo[m2+1];
        } else {
          // right OUTFLOW ghost: uv copied from col 1022; p = -p[1022]
          const int m2 = 3*((je-1)*NXC + NXC-2);
          u = uvp[m2]; v = uvp[m2+1]; p = -uvp[m2+2];
          uo = uvo[m2]; vo = uvo[m2+1];
        }

        const int e5 = 5*(je*EXC + ie);
        const float dxx=ebm[e5], dxy=ebm[e5+1], dex=ebm[e5+2], dey=ebm[e5+3];
        const float rJ = 1.f/ebm[e5+4];

        const float uh=0.5f*u,  vh=0.5f*v, ph=0.5f*p;
        const float uoh=0.5f*uo, voh=0.5f*vo;
        sUV[idx] = make_float2(uh, vh);
        sQO[idx] = make_float2(uoh, voh);
        sCN[idx] = make_float2((uh*dxx + vh*dxy)*rJ, (uh*dex + vh*dey)*rJ);
        sCO[idx] = make_float2((uoh*dxx + voh*dxy)*rJ, (uoh*dex + voh*dey)*rJ);
        sAA[idx] = make_float2((dxx*dxx + dxy*dxy)*rJ, (dex*dex + dey*dey)*rJ);
        const float pq = ph*rJ;
        sPQ[idx] = make_float2(pq*dxx, pq*dxy);
        sPE[idx] = make_float2(pq*dex, pq*dey);
        sP [idx] = ph;
        sRJ[idx] = 2.f*rdt*rJ;
      }
    }
    __syncthreads();

    // -- phase 2: 2 vertical outputs/thread, direct LDS reads (register-light)
    #pragma unroll
    for (int kk=0; kk<2; ++kk){
      const int iC = (2*ty + 1 + kk)*H_COLS + c;
      const int iW = iC-1, iE = iC+1, iS = iC-H_COLS, iN = iC+H_COLS;

      const float2 cnC=sCN[iC], cnW=sCN[iW], cnE=sCN[iE], cnS=sCN[iS], cnN=sCN[iN];
      const float2 coC=sCO[iC], coW=sCO[iW], coE=sCO[iE], coS=sCO[iS], coN=sCO[iN];

      const float Ufl = cnW.x + cnC.x, Ufr = cnC.x + cnE.x;     // true face values
      const float Vfd = cnS.y + cnC.y, Vfu = cnC.y + cnN.y;
      const float Uflo= coW.x + coC.x, Ufro= coC.x + coE.x;
      const float Vfdo= coS.y + coC.y, Vfuo= coC.y + coN.y;

      const float loss = (Ufr - Ufl + Vfu - Vfd) * cc;

      const float2 uvC=sUV[iC], uvW=sUV[iW], uvE=sUV[iE], uvS=sUV[iS], uvN=sUV[iN];
      const float u_c=uvC.x, v_c=uvC.y;

      const float cnu = (u_c+uvE.x)*Ufr - (uvW.x+u_c)*Ufl + (u_c+uvN.x)*Vfu - (uvS.x+u_c)*Vfd;
      const float cnv = (v_c+uvE.y)*Ufr - (uvW.y+v_c)*Ufl + (v_c+uvN.y)*Vfu - (uvS.y+v_c)*Vfd;

      const float2 qoC=sQO[iC], qoW=sQO[iW], qoE=sQO[iE], qoS=sQO[iS], qoN=sQO[iN];
      const float cou = (qoC.x+qoE.x)*Ufro - (qoW.x+qoC.x)*Uflo + (qoC.x+qoN.x)*Vfuo - (qoS.x+qoC.x)*Vfdo;
      const float cov = (qoC.y+qoE.y)*Ufro - (qoW.y+qoC.y)*Uflo + (qoC.y+qoN.y)*Vfuo - (qoS.y+qoC.y)*Vfdo;

      const float convu = relax*cou + (1.f-relax)*cnu;
      const float convv = relax*cov + (1.f-relax)*cnv;

      const float2 aaC=sAA[iC], aaW=sAA[iW], aaE=sAA[iE], aaS=sAA[iS], aaN=sAA[iN];
      const float axWC = aaW.x + aaC.x, axCE = aaC.x + aaE.x;
      const float aySC = aaS.y + aaC.y, ayCN = aaC.y + aaN.y;
      const float du = axCE*(uvE.x-u_c) - axWC*(u_c-uvW.x) + ayCN*(uvN.x-u_c) - aySC*(u_c-uvS.x);
      const float dv = axCE*(uvE.y-v_c) - axWC*(v_c-uvW.y) + ayCN*(uvN.y-v_c) - aySC*(v_c-uvS.y);

      const float2 pqW=sPQ[iW], pqE=sPQ[iE], peS=sPE[iS], peN=sPE[iN];
      const float gPx = (pqE.x - pqW.x) + (peN.x - peS.x);
      const float gPy = (peN.y - peS.y) + (pqE.y - pqW.y);

      const float rjd = sRJ[iC];
      const float unst_u = (u_c - qoC.x)*rjd;
      const float unst_v = (v_c - qoC.y)*rjd;

      const float momu = uc*unst_u + convc*convu + pc*gPx - dc*du;
      const float momv = uc*unst_v + convc*convv + pc*gPy - dc*dv;

      // vis: halved values -> weight 0.125
      const float2 uvSW=sUV[iS-1], uvSE=sUV[iS+1], uvNW=sUV[iN-1], uvNE=sUV[iN+1];
      const float visu=(uvSW.x+uvSE.x+uvNW.x+uvNE.x + 2.f*(uvS.x+uvW.x+uvE.x+uvN.x) + 4.f*u_c)*0.125f;
      const float visv=(uvSW.y+uvSE.y+uvNW.y+uvNE.y + 2.f*(uvS.y+uvW.y+uvE.y+uvN.y) + 4.f*v_c)*0.125f;
      const float visp=(sP[iS-1]+sP[iS+1]+sP[iN-1]+sP[iN+1]
                  + 2.f*(sP[iS]+sP[iW]+sP[iE]+sP[iN]) + 4.f*sP[iC])*0.125f;

      const int j = rt*TB_ROWS + 2*ty + kk;  // output row in [0,1023]
      const int o = j*NXC + X0e + tx;        // output col = X0e + tx
      out[o]        = loss;
      out[NN + o]   = momu;
      out[2*NN + o] = momv;
      const int vb = 3*NN + 3*o;
      out[vb]   = visu;
      out[vb+1] = visv;
      out[vb+2] = visp;
    }
  }
}

extern "C" void kernel_launch(void* const* d_in, const int* in_sizes, int n_in,
                              void* d_out, int out_size, void* d_ws, size_t ws_size,
                              hipStream_t stream) {
  const float* uvp = (const float*)d_in[0];   // original_uv
  const float* uvo = (const float*)d_in[1];   // uv_old
  const float* ndy = (const float*)d_in[2];   // node_y
  const float* ebm = (const float*)d_in[4];   // extended_block_metrics
  const float* dtg = (const float*)d_in[5];   // dt_graph
  const float* th  = (const float*)d_in[6];   // pde_theta
  const float* rl  = (const float*)d_in[7];   // relaxtion
  float* out = (float*)d_out;

  // single dispatch; kernel repeats its (idempotent) work 4x internally so
  // rocprof reports its counters above the 40us poison-fill cutoff.
  fd_kernel<<<dim3(2048), dim3(256), 0, stream>>>(uvp, uvo, ndy, ebm, dtg, th, rl, out);
}

// Round 12
// 185.955 us; speedup vs baseline: 1.3664x; 1.2622x over previous
//
#include <hip/hip_runtime.h>

// FD_discretizer on fixed 1024x1024 grid, Ex=Ey=1026 extended grid.
// Round 12: R11 with the illegal LDS address-space cast removed (corner reads
// use plain member access -> compiler emits ds_read_b64/b32 via generic ptr).
//  R10 counters (4-rep probe): fd=22.4us/rep, VALU 21%, HBM 16%, occ 16.7%,
//  VGPR 120, LDS 42.5KB (3 blocks/CU) -> latency-bound, LDS-instr heavy.
//  This round: 12 floats/node in THREE float4 planes (31.7KB -> 5 blocks/CU,
//  20 waves, launch_bounds(256,5)); phase-2 reads mostly b128 (~23/output vs
//  ~45); contravariant & pressure-metric terms recomputed at use (+~32 VALU
//  ops/output on a 21%-busy pipe). Ghost-BC staging logic unchanged (R8-R10
//  verified, absmax 0.125).
//  Planes: sA=(0.5u, 0.5v, 0.5uo, 0.5vo)
//          sM=(dxx,dxy,dex,dey)*rJ
//          sD=((dxx^2+dxy^2)*rJ, (dex^2+dey^2)*rJ, 0.5p, 2*rdt*rJ)
//  Identities: 0.5*U = sA.x*sM.x + sA.y*sM.y ; pqx = sD.z*sM.x ; etc.

#define NXC 1024               // NX == NY
#define EXC 1026               // Ex == Ey
#define NN  (NXC*NXC)

#define TB_ROWS 8
#define TB_COLS 64
#define H_ROWS  10             // TB_ROWS + 2
#define H_COLS  66             // TB_COLS + 2
#define NNODE   (H_ROWS*H_COLS)   // 660

extern "C" __global__ void __launch_bounds__(256, 5)
fd_kernel(const float* __restrict__ uvp,     // original_uv  n x 3
          const float* __restrict__ uvo,     // uv_old       n x 3
          const float* __restrict__ ndy,     // node_y       n x 3
          const float* __restrict__ ebm,     // ext metrics  n_ext x 5
          const float* __restrict__ dtg,     // dt           1
          const float* __restrict__ th,      // pde_theta    5
          const float* __restrict__ rl,      // relaxation   1
          float* __restrict__ out)
{
  const int bid = blockIdx.x;
  const int tid = threadIdx.x;

  const float dt   = dtg[0];
  const float uc   = th[0], cc = th[1], convc = th[2], pc = th[3], dc = th[4];
  const float relax= rl[0];
  const float rdt  = 1.f/dt;

  __shared__ float4 sA[NNODE];   // (0.5u, 0.5v, 0.5uo, 0.5vo)
  __shared__ float4 sM[NNODE];   // (dxx,dxy,dex,dey)*rJ
  __shared__ float4 sD[NNODE];   // (a11, a22, 0.5p, 2*rdt*rJ)

  const int ctl = bid & 15, rt = bid >> 4;   // 16 col tiles x 128 row tiles
  const int X0e = ctl*TB_COLS;               // halo ext col base (0..960)
  const int J0e = rt*TB_ROWS;                // halo ext row base (0..1016)
  const int tx = tid & 63, ty = tid >> 6;
  const int c  = 1 + tx;                     // halo col of this thread's centers

  // ---- phase 1: stage 10x66 ext-halo nodes; BC ghosts in-line (R8-verified) --
  #pragma unroll
  for (int it=0; it<3; ++it){
    const int idx = tid + it*256;
    if (idx < NNODE){
      const int r  = idx / H_COLS;
      const int c2 = idx - r*H_COLS;
      const int je = J0e + r;                // ext row in [0,1025]
      const int ie = X0e + c2;               // ext col in [0,1025]
      const bool gB=(je==0), gT=(je==EXC-1), gL=(ie==0), gR=(ie==EXC-1);
      const bool onx=gL|gR, ony=gB|gT;

      float u,v,p,uo,vo;
      if (!(onx|ony)){
        const int g3 = 3*((je-1)*NXC + (ie-1));
        u=uvp[g3]; v=uvp[g3+1]; p=uvp[g3+2];
        uo=uvo[g3]; vo=uvo[g3+1];
        if (je==EXC/2 && ie==EXC/2) p = 0.f;           // PRESS_POINT (513,513)
      } else if (onx & ony){
        const int io = gL?0:NXC-1, jo = gB?0:NXC-1;    // corner: clipped interior
        const int g3 = 3*(jo*NXC+io);
        u=uvp[g3]; v=uvp[g3+1]; p=uvp[g3+2];
        uo=uvo[g3]; vo=uvo[g3+1];
      } else if (ony){
        // bottom/top WALL ghost: uv mirrored through dummy at g1; p from g2
        const int io = ie-1;
        const int j1 = gB?0:NXC-1, j2 = gB?1:NXC-2;
        const int m1 = 3*(j1*NXC+io), m2 = 3*(j2*NXC+io);
        const bool useF = (io==NXC-1);                 // OUTFLOW g1 -> dummy=field
        const float d1u = useF? uvp[m1]   : ndy[m1];
        const float d1v = useF? uvp[m1+1] : ndy[m1+1];
        u = 2.f*d1u - uvp[m2]; v = 2.f*d1v - uvp[m2+1]; p = uvp[m2+2];
        const float e1u = useF? uvo[m1]   : ndy[m1];
        const float e1v = useF? uvo[m1+1] : ndy[m1+1];
        uo = 2.f*e1u - uvo[m2]; vo = 2.f*e1v - uvo[m2+1];
      } else if (gL){
        // left INFLOW ghost: uv mirrored through node_y at col 0; p from col 1
        const int jo = je-1;
        const int m1 = 3*(jo*NXC), m2 = m1+3;
        const float d1u = ndy[m1], d1v = ndy[m1+1];
        u = 2.f*d1u - uvp[m2]; v = 2.f*d1v - uvp[m2+1]; p = uvp[m2+2];
        uo = 2.f*d1u - uvo[m2]; vo = 2.f*d1v - uvo[m2+1];
      } else {
        // right OUTFLOW ghost: uv copied from col 1022; p = -p[1022]
        const int m2 = 3*((je-1)*NXC + NXC-2);
        u = uvp[m2]; v = uvp[m2+1]; p = -uvp[m2+2];
        uo = uvo[m2]; vo = uvo[m2+1];
      }

      const int e5 = 5*(je*EXC + ie);
      const float dxx=ebm[e5], dxy=ebm[e5+1], dex=ebm[e5+2], dey=ebm[e5+3];
      const float rJ = 1.f/ebm[e5+4];

      sA[idx] = make_float4(0.5f*u, 0.5f*v, 0.5f*uo, 0.5f*vo);
      sM[idx] = make_float4(dxx*rJ, dxy*rJ, dex*rJ, dey*rJ);
      sD[idx] = make_float4((dxx*dxx+dxy*dxy)*rJ, (dex*dex+dey*dey)*rJ,
                            0.5f*p, 2.f*rdt*rJ);
    }
  }
  __syncthreads();

  // ---- phase 2: 2 vertical outputs/thread, wide LDS reads ----
  #pragma unroll
  for (int kk=0; kk<2; ++kk){
    const int iC = (2*ty + 1 + kk)*H_COLS + c;
    const int iW = iC-1, iE = iC+1, iS = iC-H_COLS, iN = iC+H_COLS;

    const float4 aC=sA[iC], aW=sA[iW], aE=sA[iE], aS=sA[iS], aN=sA[iN];
    const float4 mC=sM[iC], mW=sM[iW], mE=sM[iE], mS=sM[iS], mN=sM[iN];
    const float4 dC=sD[iC], dW=sD[iW], dE=sD[iE], dS=sD[iS], dN=sD[iN];

    // contravariant velocities (x0.5), new & old, at needed positions
    const float cnxC = aC.x*mC.x + aC.y*mC.y, cnyC = aC.x*mC.z + aC.y*mC.w;
    const float coxC = aC.z*mC.x + aC.w*mC.y, coyC = aC.z*mC.z + aC.w*mC.w;
    const float cnxW = aW.x*mW.x + aW.y*mW.y, coxW = aW.z*mW.x + aW.w*mW.y;
    const float cnxE = aE.x*mE.x + aE.y*mE.y, coxE = aE.z*mE.x + aE.w*mE.y;
    const float cnyS = aS.x*mS.z + aS.y*mS.w, coyS = aS.z*mS.z + aS.w*mS.w;
    const float cnyN = aN.x*mN.z + aN.y*mN.w, coyN = aN.z*mN.z + aN.w*mN.w;

    const float Ufl = cnxW + cnxC, Ufr = cnxC + cnxE;   // true face values
    const float Vfd = cnyS + cnyC, Vfu = cnyC + cnyN;
    const float Uflo= coxW + coxC, Ufro= coxC + coxE;
    const float Vfdo= coyS + coyC, Vfuo= coyC + coyN;

    const float loss = (Ufr - Ufl + Vfu - Vfd) * cc;

    const float u_c=aC.x, v_c=aC.y;
    const float cnu = (u_c+aE.x)*Ufr - (aW.x+u_c)*Ufl + (u_c+aN.x)*Vfu - (aS.x+u_c)*Vfd;
    const float cnv = (v_c+aE.y)*Ufr - (aW.y+v_c)*Ufl + (v_c+aN.y)*Vfu - (aS.y+v_c)*Vfd;

    const float cou = (aC.z+aE.z)*Ufro - (aW.z+aC.z)*Uflo + (aC.z+aN.z)*Vfuo - (aS.z+aC.z)*Vfdo;
    const float cov = (aC.w+aE.w)*Ufro - (aW.w+aC.w)*Uflo + (aC.w+aN.w)*Vfuo - (aS.w+aC.w)*Vfdo;

    const float convu = relax*cou + (1.f-relax)*cnu;
    const float convv = relax*cov + (1.f-relax)*cnv;

    // diffusion (0.5 folded into uv; a11/a22 raw)
    const float axWC = dW.x + dC.x, axCE = dC.x + dE.x;
    const float aySC = dS.y + dC.y, ayCN = dC.y + dN.y;
    const float du = axCE*(aE.x-u_c) - axWC*(u_c-aW.x) + ayCN*(aN.x-u_c) - aySC*(u_c-aS.x);
    const float dv = axCE*(aE.y-v_c) - axWC*(v_c-aW.y) + ayCN*(aN.y-v_c) - aySC*(v_c-aS.y);

    // pressure gradient: pq = 0.5p * (metric*rJ)
    const float gPx = (dE.z*mE.x - dW.z*mW.x) + (dN.z*mN.z - dS.z*mS.z);
    const float gPy = (dN.z*mN.w - dS.z*mS.w) + (dE.z*mE.y - dW.z*mW.y);

    const float unst_u = (aC.x - aC.z)*dC.w;
    const float unst_v = (aC.y - aC.w)*dC.w;

    const float momu = uc*unst_u + convc*convu + pc*gPx - dc*du;
    const float momv = uc*unst_v + convc*convv + pc*gPy - dc*dv;

    // vis (halved values -> weight 0.125); corner reads via plain member access
    const float uSW=sA[iS-1].x, vSW=sA[iS-1].y;
    const float uSE=sA[iS+1].x, vSE=sA[iS+1].y;
    const float uNW=sA[iN-1].x, vNW=sA[iN-1].y;
    const float uNE=sA[iN+1].x, vNE=sA[iN+1].y;
    const float pSW=sD[iS-1].z, pSE=sD[iS+1].z, pNW=sD[iN-1].z, pNE=sD[iN+1].z;

    const float visu=(uSW+uSE+uNW+uNE + 2.f*(aS.x+aW.x+aE.x+aN.x) + 4.f*u_c)*0.125f;
    const float visv=(vSW+vSE+vNW+vNE + 2.f*(aS.y+aW.y+aE.y+aN.y) + 4.f*v_c)*0.125f;
    const float visp=(pSW+pSE+pNW+pNE + 2.f*(dS.z+dW.z+dE.z+dN.z) + 4.f*dC.z)*0.125f;

    const int j = rt*TB_ROWS + 2*ty + kk;    // output row in [0,1023]
    const int o = j*NXC + X0e + tx;          // output col = X0e + tx
    out[o]        = loss;
    out[NN + o]   = momu;
    out[2*NN + o] = momv;
    const int vb = 3*NN + 3*o;
    out[vb]   = visu;
    out[vb+1] = visv;
    out[vb+2] = visp;
  }
}

extern "C" void kernel_launch(void* const* d_in, const int* in_sizes, int n_in,
                              void* d_out, int out_size, void* d_ws, size_t ws_size,
                              hipStream_t stream) {
  const float* uvp = (const float*)d_in[0];   // original_uv
  const float* uvo = (const float*)d_in[1];   // uv_old
  const float* ndy = (const float*)d_in[2];   // node_y
  const float* ebm = (const float*)d_in[4];   // extended_block_metrics
  const float* dtg = (const float*)d_in[5];   // dt_graph
  const float* th  = (const float*)d_in[6];   // pde_theta
  const float* rl  = (const float*)d_in[7];   // relaxtion
  float* out = (float*)d_out;

  // single dispatch: 16 col tiles x 128 row tiles = 2048 blocks
  fd_kernel<<<dim3(2048), dim3(256), 0, stream>>>(uvp, uvo, ndy, ebm, dtg, th, rl, out);
}